// Round 3
// baseline (2534.329 us; speedup 1.0000x reference)
//
#include <hip/hip_runtime.h>

#define BB 128
#define TT 2048
#define II 64
#define HH 128

typedef _Float16 h2 __attribute__((ext_vector_type(2)));

__device__ __forceinline__ h2 mkh2(float a, float b) {
    h2 r; r.x = (_Float16)a; r.y = (_Float16)b; return r;
}

__device__ __forceinline__ h2 u2h(unsigned u) {
    return __builtin_bit_cast(h2, u);
}

__device__ __forceinline__ unsigned h2u(h2 v) {
    return __builtin_bit_cast(unsigned, v);
}

__device__ __forceinline__ float fdot2f(h2 a, h2 b, float c) {
#if __has_builtin(__builtin_amdgcn_fdot2)
    return __builtin_amdgcn_fdot2(a, b, c, false);
#else
    return fmaf((float)a.y, (float)b.y, fmaf((float)a.x, (float)b.x, c));
#endif
}

__device__ __forceinline__ float rcp_fast(float x) {
    return __builtin_amdgcn_rcpf(x);
}

__device__ __forceinline__ float tanh_fast(float x) {
    return fmaf(rcp_fast(1.0f + __expf(-2.0f * x)), 2.0f, -1.0f);
}

// wave-wide broadcast of lane q's dword (q compile-time const via unroll)
__device__ __forceinline__ h2 bcast(unsigned v, int q) {
    return u2h((unsigned)__builtin_amdgcn_readlane((int)v, q));
}

// DPP quad_perm cross-lane (within groups of 4 lanes)
template <int CTRL>
__device__ __forceinline__ float dppq(float x) {
#if __has_builtin(__builtin_amdgcn_update_dpp)
    int i = __builtin_bit_cast(int, x);
    int r = __builtin_amdgcn_update_dpp(i, i, CTRL, 0xF, 0xF, true);
    return __builtin_bit_cast(float, r);
#else
    return __shfl_xor(x, (CTRL == 177) ? 1 : (CTRL == 78) ? 2 : 3, 4);
#endif
}

// One WG per batch; 256 threads (4 waves, 1/SIMD). Each thread owns 2 gate
// rows: (gt, j1=w*16+k) and (gt, j2=j1+64). z = [x_t fp16x2 (32 dw) | h fp16
// (64 dw)] lives in LDS; each wave pulls it with 2 cooperative ds_read_b32
// and broadcasts via v_readlane -> SGPR into v_dot2 (no LDS broadcast).
// Gate exchange within each quad via DPP; one barrier per step.
__global__ __launch_bounds__(256, 1) void lstm_fused_kernel(
    const float* __restrict__ input,  // [B,T,I]
    const float* __restrict__ h0,     // [B,H]
    const float* __restrict__ c0,     // [B,H]
    const float* __restrict__ W_ih,   // [4H,I]
    const float* __restrict__ W_hh,   // [4H,H]
    const float* __restrict__ b_ih,   // [4H]
    const float* __restrict__ b_hh,   // [4H]
    float* __restrict__ out)          // [B*H] h_last, then [B,T,H] encoded
{
    // dwords [0..31] = x_t (fp16x2), dwords [32..95] = h (fp16, 128 vals)
    __shared__ __align__(16) unsigned s_z[2][96];

    const int tid  = threadIdx.x;
    const int b    = blockIdx.x;
    const int w    = tid >> 6;
    const int lane = tid & 63;
    const int gt   = lane & 3;                 // 0=i 1=f 2=g 3=o
    const int k    = lane >> 2;                // [0,16)
    const int j1   = (w << 4) | k;             // [0,64)
    const int j2   = j1 + 64;                  // [64,128)
    const int row1 = (gt << 7) | j1;
    const int row2 = (gt << 7) | j2;

    // ---- weights: 2 rows of W_ih (32 dw each... 32 h2) + 2 rows of W_hh ----
    h2 wx1[II / 2], wx2[II / 2];   // 32 + 32 regs
    h2 wh1[HH / 2], wh2[HH / 2];   // 64 + 64 regs
    {
        const float4* p1 = reinterpret_cast<const float4*>(W_ih + row1 * II);
        const float4* p2 = reinterpret_cast<const float4*>(W_ih + row2 * II);
#pragma unroll
        for (int q = 0; q < II / 4; ++q) {
            float4 a = p1[q], c = p2[q];
            wx1[2 * q] = mkh2(a.x, a.y); wx1[2 * q + 1] = mkh2(a.z, a.w);
            wx2[2 * q] = mkh2(c.x, c.y); wx2[2 * q + 1] = mkh2(c.z, c.w);
        }
    }
    {
        const float4* p1 = reinterpret_cast<const float4*>(W_hh + row1 * HH);
        const float4* p2 = reinterpret_cast<const float4*>(W_hh + row2 * HH);
#pragma unroll
        for (int q = 0; q < HH / 4; ++q) {
            float4 a = p1[q], c = p2[q];
            wh1[2 * q] = mkh2(a.x, a.y); wh1[2 * q + 1] = mkh2(a.z, a.w);
            wh2[2 * q] = mkh2(c.x, c.y); wh2[2 * q + 1] = mkh2(c.z, c.w);
        }
    }
    const float bias1 = b_ih[row1] + b_hh[row1];
    const float bias2 = b_ih[row2] + b_hh[row2];

    // ---- state init ----
    float c1 = c0[(size_t)b * HH + j1];
    float c2 = c0[(size_t)b * HH + j2];
    if (tid < 64) {
        float2 hv = reinterpret_cast<const float2*>(h0 + (size_t)b * HH)[tid];
        s_z[0][32 + tid] = h2u(mkh2(hv.x, hv.y));
    }

    // ---- x prefetch (threads 0..31 of wave 0) ----
    const float2* xin = reinterpret_cast<const float2*>(input) + (size_t)b * TT * 32 + tid;
    float2 xb0, xb1, xb2, xb3;
    if (tid < 32) {
        xb0 = xin[(size_t)0 * 32];
        xb1 = xin[(size_t)1 * 32];
        xb2 = xin[(size_t)2 * 32];
        xb3 = xin[(size_t)3 * 32];
        s_z[0][tid] = h2u(mkh2(xb0.x, xb0.y));  // stage x_0
        xb0 = xin[(size_t)4 * 32];              // xb0 -> x_4
    }
    __syncthreads();

    float* out_h = out;            // [B*H]
    float* out_e = out + BB * HH;  // [B*T*H]
    float hl1 = 0.0f, hl2 = 0.0f;

    auto step = [&](int t, float2& xbn) {
        const int cb = t & 1, nb = cb ^ 1;

        if (tid < 32) {
            s_z[nb][tid] = h2u(mkh2(xbn.x, xbn.y));
            int tn = t + 5; if (tn > TT - 1) tn = TT - 1;   // clamped, harmless
            xbn = xin[(size_t)tn * 32];
        }

        // cooperative z read: 2 LDS instructions per wave
        unsigned v0 = s_z[cb][lane];              // dwords 0..63
        unsigned v1 = s_z[cb][64 + (lane & 31)];  // dwords 64..95

        float a10 = bias1, a11 = 0.f, a12 = 0.f, a13 = 0.f;
        float a20 = bias2, a21 = 0.f, a22 = 0.f, a23 = 0.f;

#pragma unroll
        for (int q = 0; q < 32; ++q) {   // x part: z dwords 0..31
            h2 z = bcast(v0, q);
            switch (q & 3) {
                case 0: a10 = fdot2f(wx1[q], z, a10); a20 = fdot2f(wx2[q], z, a20); break;
                case 1: a11 = fdot2f(wx1[q], z, a11); a21 = fdot2f(wx2[q], z, a21); break;
                case 2: a12 = fdot2f(wx1[q], z, a12); a22 = fdot2f(wx2[q], z, a22); break;
                default: a13 = fdot2f(wx1[q], z, a13); a23 = fdot2f(wx2[q], z, a23); break;
            }
        }
#pragma unroll
        for (int p = 0; p < 32; ++p) {   // h part 1: z dwords 32..63
            h2 z = bcast(v0, 32 + p);
            switch (p & 3) {
                case 0: a10 = fdot2f(wh1[p], z, a10); a20 = fdot2f(wh2[p], z, a20); break;
                case 1: a11 = fdot2f(wh1[p], z, a11); a21 = fdot2f(wh2[p], z, a21); break;
                case 2: a12 = fdot2f(wh1[p], z, a12); a22 = fdot2f(wh2[p], z, a22); break;
                default: a13 = fdot2f(wh1[p], z, a13); a23 = fdot2f(wh2[p], z, a23); break;
            }
        }
#pragma unroll
        for (int p = 32; p < 64; ++p) {  // h part 2: z dwords 64..95
            h2 z = bcast(v1, p - 32);
            switch (p & 3) {
                case 0: a10 = fdot2f(wh1[p], z, a10); a20 = fdot2f(wh2[p], z, a20); break;
                case 1: a11 = fdot2f(wh1[p], z, a11); a21 = fdot2f(wh2[p], z, a21); break;
                case 2: a12 = fdot2f(wh1[p], z, a12); a22 = fdot2f(wh2[p], z, a22); break;
                default: a13 = fdot2f(wh1[p], z, a13); a23 = fdot2f(wh2[p], z, a23); break;
            }
        }
        float g1 = (a10 + a11) + (a12 + a13);
        float g2 = (a20 + a21) + (a22 + a23);

        // activation for own gate type (gt==2 -> tanh, else sigmoid)
        float p1 = (gt == 2) ? 2.0f * g1 : g1;
        float p2 = (gt == 2) ? 2.0f * g2 : g2;
        float s1 = rcp_fast(1.0f + __expf(-p1));
        float s2 = rcp_fast(1.0f + __expf(-p2));
        float act1 = (gt == 2) ? fmaf(s1, 2.0f, -1.0f) : s1;
        float act2 = (gt == 2) ? fmaf(s2, 2.0f, -1.0f) : s2;

        // quad butterfly for both elements
        float x1a = dppq<177>(act1), x1b = dppq<78>(act1), x1c = dppq<27>(act1);
        float x2a = dppq<177>(act2), x2b = dppq<78>(act2), x2c = dppq<27>(act2);

        auto gates = [&](float v0_, float v1_, float v2_, float v3_,
                         float& iv, float& fv, float& gv, float& ov) {
            float sA = (gt & 1) ? v1_ : v0_;
            float sB = (gt & 1) ? v3_ : v2_;
            float sC = (gt & 1) ? v0_ : v1_;
            float sD = (gt & 1) ? v2_ : v3_;
            iv = (gt & 2) ? sB : sA;
            gv = (gt & 2) ? sA : sB;
            fv = (gt & 2) ? sD : sC;
            ov = (gt & 2) ? sC : sD;
        };
        float iv1, fv1, gv1, ov1, iv2, fv2, gv2, ov2;
        gates(act1, x1a, x1b, x1c, iv1, fv1, gv1, ov1);
        gates(act2, x2a, x2b, x2c, iv2, fv2, gv2, ov2);

        c1 = fmaf(fv1, c1, iv1 * gv1);
        c2 = fmaf(fv2, c2, iv2 * gv2);
        float hv1 = ov1 * tanh_fast(c1);
        float hv2 = ov2 * tanh_fast(c2);
        hl1 = hv1; hl2 = hv2;

        _Float16* zh = reinterpret_cast<_Float16*>(&s_z[nb][32]);
        if (gt == 0) zh[j1] = (_Float16)hv1;
        if (gt == 1) zh[j2] = (_Float16)hv2;
        if (gt == 2) out_e[((size_t)b * TT + t) * HH + j1] = hv1;
        if (gt == 3) out_e[((size_t)b * TT + t) * HH + j2] = hv2;

        __syncthreads();
    };

    for (int t0 = 0; t0 < TT; t0 += 4) {
        step(t0 + 0, xb1);
        step(t0 + 1, xb2);
        step(t0 + 2, xb3);
        step(t0 + 3, xb0);
    }

    if (gt == 0) out_h[(size_t)b * HH + j1] = hl1;
    if (gt == 1) out_h[(size_t)b * HH + j2] = hl2;
}

extern "C" void kernel_launch(void* const* d_in, const int* in_sizes, int n_in,
                              void* d_out, int out_size, void* d_ws, size_t ws_size,
                              hipStream_t stream) {
    const float* input = (const float*)d_in[0];
    const float* h0    = (const float*)d_in[1];
    const float* c0    = (const float*)d_in[2];
    const float* W_ih  = (const float*)d_in[3];
    const float* W_hh  = (const float*)d_in[4];
    const float* b_ih  = (const float*)d_in[5];
    const float* b_hh  = (const float*)d_in[6];
    float* out = (float*)d_out;

    hipLaunchKernelGGL(lstm_fused_kernel, dim3(BB), dim3(256), 0, stream,
                       input, h0, c0, W_ih, W_hh, b_ih, b_hh, out);
}